// Round 2
// 84.648 us; speedup vs baseline: 1.0195x; 1.0195x over previous
//
#include <hip/hip_runtime.h>
#include <math.h>

#define N_PL 16
#define NT   17      // N_PL+1
#define OBJ  10
#define M    36
#define SPB  4       // samples per block
#define BLK  64      // one wave per block; 16 lanes per sample
#define CSTR 12      // dedup/sim row stride (48 B -> b128-aligned rows)

// packed (i<<4)|j pair tables
__constant__ unsigned char c_p55[55] = {
 0x00,0x01,0x02,0x03,0x04,0x05,0x06,0x07,0x08,0x09,
 0x11,0x12,0x13,0x14,0x15,0x16,0x17,0x18,0x19,
 0x22,0x23,0x24,0x25,0x26,0x27,0x28,0x29,
 0x33,0x34,0x35,0x36,0x37,0x38,0x39,
 0x44,0x45,0x46,0x47,0x48,0x49,
 0x55,0x56,0x57,0x58,0x59,
 0x66,0x67,0x68,0x69,
 0x77,0x78,0x79,
 0x88,0x89,
 0x99};
__constant__ unsigned char c_p45[45] = {
 0x01,0x02,0x03,0x04,0x05,0x06,0x07,0x08,0x09,
 0x12,0x13,0x14,0x15,0x16,0x17,0x18,0x19,
 0x23,0x24,0x25,0x26,0x27,0x28,0x29,
 0x34,0x35,0x36,0x37,0x38,0x39,
 0x45,0x46,0x47,0x48,0x49,
 0x56,0x57,0x58,0x59,
 0x67,0x68,0x69,
 0x78,0x79,
 0x89};

// lookup with y = 16*x already computed; no clamp (all callers guarantee
// y in [-4e-6, 16.007): (int) truncs toward 0, row 16 of the fused table
// holds (cs[16], wn[16]) which exactly reproduces the reference clamp.
__device__ __forceinline__ float plinY(const float2* tb, float y) {
    int idx = (int)y;
    float f = y - (float)idx;
    float2 cw = tb[idx];
    return __builtin_fmaf(f, cw.y, cw.x);
}

// plin of 1-|a-b|, a,b in [0,1]: y = fma(-|a-b|, 16, 16) in [0,16]
__device__ __forceinline__ float plinD(const float2* tb, float a, float b) {
    float y = __builtin_fmaf(-fabsf(a - b), 16.f, 16.f);
    int idx = (int)y;
    float f = y - (float)idx;
    float2 cw = tb[idx];
    return __builtin_fmaf(f, cw.y, cw.x);
}

// sortable key: primary = sign-flipped float bits, secondary = 63-index
__device__ __forceinline__ unsigned long long mkkey(float v, int m) {
    unsigned int b = __float_as_uint(v);
    unsigned int u = b ^ (0x80000000u | (unsigned int)((int)b >> 31));
    return ((unsigned long long)u << 32) | (unsigned int)(63 - m);
}

__global__ __launch_bounds__(BLK, 4) void counter_kernel(
    const float* __restrict__ boxes,   // [n,4,36]
    const float* __restrict__ attn,    // [n,36]
    const float* __restrict__ ws,      // [8,17]
    float* __restrict__ out,           // [n,11]
    int n)
{
    __shared__ float2 s_tab2[8 * NT];          // fused (cs, wn+1) tables
    __shared__ float4 s_bx[SPB][OBJ];          // x0,y0,x1,y1
    __shared__ float4 s_aa[SPB][OBJ];          // (att, area, 16*att, 0)
    __shared__ __align__(16) unsigned long long s_key[SPB][M];  // sort keys
    __shared__ float  s_ded[SPB][CSTR * OBJ];  // symmetric, stride-12 rows
    __shared__ float  s_sim[SPB][CSTR * OBJ];  // stride-12 rows, diag zeroed
    __shared__ float  s_rf[SPB][OBJ];          // 1/row_sims

    const int tid = threadIdx.x;
    const int g = tid & 15;
    const int p = tid >> 4;

    int s = blockIdx.x * SPB + p;
    const bool active = (s < n);
    if (!active) s = n - 1;

    const float* arow = attn + (size_t)s * M;
    const float* brow = boxes + (size_t)s * (4 * M);

    // ---- my attention values (1 per candidate, no redundant stream) ----
    float mv0 = arow[g];
    float mv1 = arow[g + 16];
    float mv2 = (g < 4) ? arow[g + 32] : 0.f;

    // ---- unconditional early box prefetch: hides HBM latency under rank.
    // Selection touches nearly every line of the 576B row anyway.
    float bx0[4], bx1[4], bx2[4];
    #pragma unroll
    for (int r = 0; r < 4; ++r) bx0[r] = brow[r * M + g];
    #pragma unroll
    for (int r = 0; r < 4; ++r) bx1[r] = brow[r * M + g + 16];
    #pragma unroll
    for (int r = 0; r < 4; ++r) bx2[r] = (g < 4) ? brow[r * M + g + 32] : 0.f;

    // ---- build keys ONCE, share via LDS (kills 16x redundant mkkey) ----
    unsigned long long k0 = mkkey(mv0, g);
    unsigned long long k1 = mkkey(mv1, g + 16);
    unsigned long long k2 = (g < 4) ? mkkey(mv2, g + 32) : 0ull;  // 0 => rank 36
    s_key[p][g] = k0;
    s_key[p][g + 16] = k1;
    if (g < 4) s_key[p][g + 32] = k2;

    // ---- in-block table prep: lanes 0..7 (unchanged numerics) ----
    if (tid < 8) {
        float w[NT]; float sum = 0.f;
        #pragma unroll
        for (int k = 0; k < NT; ++k) { w[k] = fabsf(ws[tid * NT + k]); sum += w[k]; }
        float rs = 1.f / sum;
        float wn[NT];
        #pragma unroll
        for (int k = 0; k < NT; ++k) wn[k] = w[k] * rs;
        float c = 0.f;
        #pragma unroll
        for (int k = 0; k < NT; ++k) {
            c += wn[k];
            s_tab2[tid * NT + k] = make_float2(c, wn[k < N_PL ? k + 1 : N_PL]);
        }
    }
    __syncthreads();   // tables + keys ready

    // ---- rank from shared keys: 18 b128 broadcast reads + 108 u64 cmps ----
    int r0 = 0, r1 = 0, r2 = 0;
    const ulonglong2* kp = (const ulonglong2*)(&s_key[p][0]);
    #pragma unroll
    for (int w = 0; w < 18; ++w) {
        ulonglong2 kk = kp[w];
        r0 += (kk.x > k0); r0 += (kk.y > k0);
        r1 += (kk.x > k1); r1 += (kk.y > k1);
        r2 += (kk.x > k2); r2 += (kk.y > k2);
    }

    // ---- scatter selected (rank<10 -> unique slot) ----
    float mA = 0.f;
    if (r0 < OBJ) {
        float a = 1.f / (1.f + __expf(-mv0));
        float a16 = 16.f * a;
        mA += fabsf(plinY(s_tab2 + 5 * NT, a16) - 0.5f);
        s_bx[p][r0] = make_float4(bx0[0], bx0[1], bx0[2], bx0[3]);
        s_aa[p][r0] = make_float4(a,
            fmaxf(bx0[2] - bx0[0], 0.f) * fmaxf(bx0[3] - bx0[1], 0.f), a16, 0.f);
    }
    if (r1 < OBJ) {
        float a = 1.f / (1.f + __expf(-mv1));
        float a16 = 16.f * a;
        mA += fabsf(plinY(s_tab2 + 5 * NT, a16) - 0.5f);
        s_bx[p][r1] = make_float4(bx1[0], bx1[1], bx1[2], bx1[3]);
        s_aa[p][r1] = make_float4(a,
            fmaxf(bx1[2] - bx1[0], 0.f) * fmaxf(bx1[3] - bx1[1], 0.f), a16, 0.f);
    }
    if (r2 < OBJ) {
        float a = 1.f / (1.f + __expf(-mv2));
        float a16 = 16.f * a;
        mA += fabsf(plinY(s_tab2 + 5 * NT, a16) - 0.5f);
        s_bx[p][r2] = make_float4(bx2[0], bx2[1], bx2[2], bx2[3]);
        s_aa[p][r2] = make_float4(a,
            fmaxf(bx2[2] - bx2[0], 0.f) * fmaxf(bx2[3] - bx2[1], 0.f), a16, 0.f);
    }
    __syncthreads();

    // ---- pass A: 4 of 55 (i<=j) pairs; shared (idx,f) prep for 5 lookups ----
    float mD = 0.f;
    float sc_loc[4];
    unsigned int pks = 0;
    #pragma unroll
    for (int t = 0; t < 4; ++t) {
        int q = g + 16 * t;
        bool act = (q < 55);
        int pk = c_p55[act ? q : 0];
        pks |= (unsigned int)pk << (8 * t);
        int i = pk >> 4, j = pk & 15;
        float4 bi = s_bx[p][i], bj = s_bx[p][j];
        float4 ai = s_aa[p][i], aj = s_aa[p][j];
        float wx = fminf(bi.z, bj.z) - fmaxf(bi.x, bj.x);
        float wy = fminf(bi.w, bj.w) - fmaxf(bi.y, bj.y);
        float inter = fmaxf(wx, 0.f) * fmaxf(wy, 0.f);
        float un = ai.y + aj.y - inter + 1e-12f;
        float iou = inter * __builtin_amdgcn_rcpf(un);
        float yd = __builtin_fmaf(iou, -16.f, 16.f);   // 16*(1-iou)
        int id_ = (int)yd; float fd = yd - (float)id_;
        float yr = ai.z * aj.x;                        // 16*relev
        int ir_ = (int)yr; float fr = yr - (float)ir_;
        float2 c0 = s_tab2[ir_];
        float2 c1 = s_tab2[NT + id_];
        float2 c3 = s_tab2[3 * NT + ir_];
        float2 c4 = s_tab2[4 * NT + id_];
        float2 c6 = s_tab2[6 * NT + id_];
        sc_loc[t] = __builtin_fmaf(fr, c0.y, c0.x) * __builtin_fmaf(fd, c1.y, c1.x);
        float dd  = __builtin_fmaf(fr, c3.y, c3.x) * __builtin_fmaf(fd, c4.y, c4.x);
        float dc  = fabsf(__builtin_fmaf(fd, c6.y, c6.x) - 0.5f);
        if (act) {
            s_ded[p][i * CSTR + j] = dd;
            s_ded[p][j * CSTR + i] = dd;
            mD += (i != j) ? 2.f * dc : dc;
        }
    }
    __syncthreads();

    // ---- pass B: 3 of 45 (i<j) pairs -> sim matrix; also zero diag ----
    if (g < OBJ) s_sim[p][g * CSTR + g] = 0.f;
    #pragma unroll
    for (int t = 0; t < 3; ++t) {
        int q = g + 16 * t;
        bool act = (q < 45);
        int pk = c_p45[act ? q : 0];
        int i = pk >> 4, j = pk & 15;
        float4 ai = s_aa[p][i], aj = s_aa[p][j];
        const float2* tb2 = s_tab2 + 2 * NT;
        float prod = plinD(tb2, ai.x, aj.x);
        const float* ci = &s_ded[p][i * CSTR];
        const float* cj = &s_ded[p][j * CSTR];
        float4 ci0 = *(const float4*)ci;
        float4 ci1 = *(const float4*)(ci + 4);
        float2 ci2 = *(const float2*)(ci + 8);
        float4 cj0 = *(const float4*)cj;
        float4 cj1 = *(const float4*)(cj + 4);
        float2 cj2 = *(const float2*)(cj + 8);
        prod *= plinD(tb2, ci0.x, cj0.x);
        prod *= plinD(tb2, ci0.y, cj0.y);
        prod *= plinD(tb2, ci0.z, cj0.z);
        prod *= plinD(tb2, ci0.w, cj0.w);
        prod *= plinD(tb2, ci1.x, cj1.x);
        prod *= plinD(tb2, ci1.y, cj1.y);
        prod *= plinD(tb2, ci1.z, cj1.z);
        prod *= plinD(tb2, ci1.w, cj1.w);
        prod *= plinD(tb2, ci2.x, cj2.x);
        prod *= plinD(tb2, ci2.y, cj2.y);
        if (act) {
            s_sim[p][i * CSTR + j] = prod;
            s_sim[p][j * CSTR + i] = prod;
        }
    }
    __syncthreads();

    // ---- row_sims: lane g sums its row (diag closed form: cs2[16]^11) ----
    if (g < OBJ) {
        float c16 = s_tab2[2 * NT + N_PL].x;
        float c2 = c16 * c16, c4 = c2 * c2, c8 = c4 * c4;
        float diag = c8 * c2 * c16;
        const float* rw = &s_sim[p][g * CSTR];
        float4 q0 = *(const float4*)rw;
        float4 q1 = *(const float4*)(rw + 4);
        float2 q2 = *(const float2*)(rw + 8);
        float sum = diag + q0.x + q0.y + q0.z + q0.w
                         + q1.x + q1.y + q1.z + q1.w + q2.x + q2.y;
        s_rf[p][g] = 1.f / sum;
    }
    __syncthreads();

    // ---- pass C ----
    float tot = 0.f;
    #pragma unroll
    for (int t = 0; t < 4; ++t) {
        int q = g + 16 * t;
        bool act = (q < 55);
        int pk = (int)((pks >> (8 * t)) & 255u);
        int i = pk >> 4, j = pk & 15;
        float term = sc_loc[t] * s_rf[p][i] * s_rf[p][j];
        if (act) tot += (i != j) ? 2.f * term : term;
    }
    if (g < OBJ) {
        float4 aa = s_aa[p][g];
        float y = aa.z * aa.x;             // 16*att^2
        tot += plinY(s_tab2, y) * s_rf[p][g];
    }
    float carg16 = __builtin_fmaf(mD, 0.16f, mA * 1.6f);  // 16*(mA/10 + mD/100)
    tot    += __shfl_xor(tot, 1);    tot    += __shfl_xor(tot, 2);
    tot    += __shfl_xor(tot, 4);    tot    += __shfl_xor(tot, 8);
    carg16 += __shfl_xor(carg16, 1); carg16 += __shfl_xor(carg16, 2);
    carg16 += __shfl_xor(carg16, 4); carg16 += __shfl_xor(carg16, 8);

    float total = sqrtf(tot + 1e-20f);
    float conf = plinY(s_tab2 + 7 * NT, carg16);
    float scl = fminf(fmaxf(total, 0.f), 10.f);
    int i0 = (int)scl;
    float f = scl - (float)i0;
    int lo = i0 < OBJ ? i0 : OBJ;
    int hi = (i0 + 1) < OBJ ? (i0 + 1) : OBJ;

    if (active && g <= OBJ) {
        float vv = ((g == lo) ? (1.f - f) : 0.f) + ((g == hi) ? f : 0.f);
        out[(size_t)s * (OBJ + 1) + g] = vv * conf;
    }
}

extern "C" void kernel_launch(void* const* d_in, const int* in_sizes, int n_in,
                              void* d_out, int out_size, void* d_ws, size_t ws_size,
                              hipStream_t stream) {
    const float* boxes = (const float*)d_in[0];
    const float* attn  = (const float*)d_in[1];
    const float* ws    = (const float*)d_in[2];
    float* out = (float*)d_out;
    int n = in_sizes[1] / M;
    int blocks = (n + SPB - 1) / SPB;
    hipLaunchKernelGGL(counter_kernel, dim3(blocks), dim3(BLK), 0, stream,
                       boxes, attn, ws, out, n);
}